// Round 1
// baseline (92.760 us; speedup 1.0000x reference)
//
#include <hip/hip_runtime.h>
#include <math.h>

// BondOrderConv: out[e] = sigmoid( nf[src[e]]·W_src + b_src
//                                + nf[dst[e]]·W_dst + b_dst
//                                + ef[e]·W_edge + b_edge )
// F = 256. Memory-bound on edge_feats (327.7 MB). Floor ~54 us @ 6.3 TB/s.

#define FDIM 256
#define F4   (FDIM / 4)   // 64 float4 per row == one float4 per lane of a wave

// Kernel 1: per-node gate scalars. One wave per node; lane i owns floats [4i,4i+4).
__global__ void node_gates_kernel(const float* __restrict__ nf,
                                  const float* __restrict__ W_src,
                                  const float* __restrict__ W_dst,
                                  const float* __restrict__ b_src,
                                  const float* __restrict__ b_dst,
                                  float* __restrict__ e_src,
                                  float* __restrict__ e_dst,
                                  int n_nodes) {
    const int lane   = threadIdx.x & 63;
    const int wave   = (blockIdx.x * blockDim.x + threadIdx.x) >> 6;
    const int nwaves = (gridDim.x * blockDim.x) >> 6;

    const float4 ws = reinterpret_cast<const float4*>(W_src)[lane];
    const float4 wd = reinterpret_cast<const float4*>(W_dst)[lane];
    const float bs = b_src[0];
    const float bd = b_dst[0];

    for (int n = wave; n < n_nodes; n += nwaves) {
        const float4 x = reinterpret_cast<const float4*>(nf)[(size_t)n * F4 + lane];
        float ss = x.x * ws.x + x.y * ws.y + x.z * ws.z + x.w * ws.w;
        float sd = x.x * wd.x + x.y * wd.y + x.z * wd.z + x.w * wd.w;
        #pragma unroll
        for (int off = 1; off < 64; off <<= 1) {
            ss += __shfl_xor(ss, off, 64);
            sd += __shfl_xor(sd, off, 64);
        }
        if (lane == 0) {
            e_src[n] = ss + bs;
            e_dst[n] = sd + bd;
        }
    }
}

// Kernel 2: per-edge fused gate + gather + sigmoid. One wave per edge (grid-stride).
__global__ void edge_gate_kernel(const float* __restrict__ ef,
                                 const int* __restrict__ src,
                                 const int* __restrict__ dst,
                                 const float* __restrict__ W_edge,
                                 const float* __restrict__ b_edge,
                                 const float* __restrict__ e_src,
                                 const float* __restrict__ e_dst,
                                 float* __restrict__ out,
                                 int n_edges) {
    const int lane   = threadIdx.x & 63;
    const int wave   = (blockIdx.x * blockDim.x + threadIdx.x) >> 6;
    const int nwaves = (gridDim.x * blockDim.x) >> 6;

    const float4 we = reinterpret_cast<const float4*>(W_edge)[lane];
    const float be = b_edge[0];

    for (int e = wave; e < n_edges; e += nwaves) {
        const float4 x = reinterpret_cast<const float4*>(ef)[(size_t)e * F4 + lane];
        float s = x.x * we.x + x.y * we.y + x.z * we.z + x.w * we.w;
        #pragma unroll
        for (int off = 1; off < 64; off <<= 1) {
            s += __shfl_xor(s, off, 64);
        }
        if (lane == 0) {
            const float m = s + be + e_src[src[e]] + e_dst[dst[e]];
            out[e] = 1.0f / (1.0f + expf(-m));
        }
    }
}

extern "C" void kernel_launch(void* const* d_in, const int* in_sizes, int n_in,
                              void* d_out, int out_size, void* d_ws, size_t ws_size,
                              hipStream_t stream) {
    const float* node_feats = (const float*)d_in[0];
    const float* edge_feats = (const float*)d_in[1];
    const int*   src        = (const int*)d_in[2];
    const int*   dst        = (const int*)d_in[3];
    const float* W_src      = (const float*)d_in[4];
    const float* b_src      = (const float*)d_in[5];
    const float* W_dst      = (const float*)d_in[6];
    const float* b_dst      = (const float*)d_in[7];
    const float* W_edge     = (const float*)d_in[8];
    const float* b_edge     = (const float*)d_in[9];

    const int n_nodes = in_sizes[0] / FDIM;
    const int n_edges = in_sizes[2];

    float* e_src = (float*)d_ws;
    float* e_dst = e_src + n_nodes;

    // Kernel 1: 10000 waves -> 2500 blocks of 256 (4 waves/block).
    {
        int waves_needed = n_nodes;
        int blocks = (waves_needed + 3) / 4;   // 4 waves per 256-thread block
        if (blocks > 2048) blocks = 2048;
        node_gates_kernel<<<blocks, 256, 0, stream>>>(
            node_feats, W_src, W_dst, b_src, b_dst, e_src, e_dst, n_nodes);
    }

    // Kernel 2: grid-stride, capped at 2048 blocks (8192 waves, ~39 edges each).
    {
        int blocks = 2048;
        edge_gate_kernel<<<blocks, 256, 0, stream>>>(
            edge_feats, src, dst, W_edge, b_edge, e_src, e_dst,
            (float*)d_out, n_edges);
    }
}

// Round 2
// 62.778 us; speedup vs baseline: 1.4776x; 1.4776x over previous
//
#include <hip/hip_runtime.h>
#include <math.h>

// BondOrderConv: out[e] = sigmoid( nf[src[e]]·W_src + b_src
//                                + nf[dst[e]]·W_dst + b_dst
//                                + ef[e]·W_edge + b_edge )
// F = 256 f32. Memory-bound on edge_feats (327.7 MB). Floor ~54 us @ 6.3 TB/s.
//
// Layout: 16 lanes per row, 4 rows per wave-iteration.
//   lane = 16*sub + i  (sub = which row of the 4, i = column lane)
//   lane covers float4 columns i, i+16, i+32, i+48  -> 4 indep loads in flight
//   reduce = 4-step width-16 butterfly; one swizzle reduces 4 rows at once.

#define FDIM 256
#define F4   (FDIM / 4)   // 64 float4 per row

__device__ __forceinline__ float dot4(float4 a, float4 b) {
    return a.x * b.x + a.y * b.y + a.z * b.z + a.w * b.w;
}

// Kernel 1: per-node gate scalars (two dots per node).
__global__ void node_gates_kernel(const float* __restrict__ nf,
                                  const float* __restrict__ W_src,
                                  const float* __restrict__ W_dst,
                                  const float* __restrict__ b_src,
                                  const float* __restrict__ b_dst,
                                  float* __restrict__ e_src,
                                  float* __restrict__ e_dst,
                                  int n_nodes) {
    const int lane   = threadIdx.x & 63;
    const int sub    = lane >> 4;        // which of 4 nodes
    const int i      = lane & 15;        // column lane within node
    const int wave   = (blockIdx.x * blockDim.x + threadIdx.x) >> 6;
    const int nwaves = (gridDim.x * blockDim.x) >> 6;

    const float4* Ws4 = reinterpret_cast<const float4*>(W_src);
    const float4* Wd4 = reinterpret_cast<const float4*>(W_dst);
    const float4 ws0 = Ws4[i], ws1 = Ws4[i + 16], ws2 = Ws4[i + 32], ws3 = Ws4[i + 48];
    const float4 wd0 = Wd4[i], wd1 = Wd4[i + 16], wd2 = Wd4[i + 32], wd3 = Wd4[i + 48];
    const float bs = b_src[0];
    const float bd = b_dst[0];

    const int ngroups = (n_nodes + 3) >> 2;
    for (int g = wave; g < ngroups; g += nwaves) {
        const int n = g * 4 + sub;
        if (n >= n_nodes) continue;
        const float4* row = reinterpret_cast<const float4*>(nf) + (size_t)n * F4;
        const float4 x0 = row[i], x1 = row[i + 16], x2 = row[i + 32], x3 = row[i + 48];
        float ss = dot4(x0, ws0) + dot4(x1, ws1) + dot4(x2, ws2) + dot4(x3, ws3);
        float sd = dot4(x0, wd0) + dot4(x1, wd1) + dot4(x2, wd2) + dot4(x3, wd3);
        #pragma unroll
        for (int off = 1; off < 16; off <<= 1) {
            ss += __shfl_xor(ss, off, 64);
            sd += __shfl_xor(sd, off, 64);
        }
        if (i == 0) {
            e_src[n] = ss + bs;
            e_dst[n] = sd + bd;
        }
    }
}

// Kernel 2: per-edge gate + gather + sigmoid.
__global__ void edge_gate_kernel(const float* __restrict__ ef,
                                 const int* __restrict__ src,
                                 const int* __restrict__ dst,
                                 const float* __restrict__ W_edge,
                                 const float* __restrict__ b_edge,
                                 const float* __restrict__ e_src,
                                 const float* __restrict__ e_dst,
                                 float* __restrict__ out,
                                 int n_edges) {
    const int lane   = threadIdx.x & 63;
    const int sub    = lane >> 4;        // which of 4 edges
    const int i      = lane & 15;        // column lane within edge
    const int wave   = (blockIdx.x * blockDim.x + threadIdx.x) >> 6;
    const int nwaves = (gridDim.x * blockDim.x) >> 6;

    const float4* We4 = reinterpret_cast<const float4*>(W_edge);
    const float4 w0 = We4[i], w1 = We4[i + 16], w2 = We4[i + 32], w3 = We4[i + 48];
    const float be = b_edge[0];

    const int ngroups = (n_edges + 3) >> 2;
    for (int g = wave; g < ngroups; g += nwaves) {
        const int e = g * 4 + sub;
        if (e >= n_edges) continue;
        const float4* row = reinterpret_cast<const float4*>(ef) + (size_t)e * F4;
        const float4 x0 = row[i], x1 = row[i + 16], x2 = row[i + 32], x3 = row[i + 48];
        float s = dot4(x0, w0) + dot4(x1, w1) + dot4(x2, w2) + dot4(x3, w3);
        #pragma unroll
        for (int off = 1; off < 16; off <<= 1) {
            s += __shfl_xor(s, off, 64);
        }
        if (i == 0) {
            const float m = s + be + e_src[src[e]] + e_dst[dst[e]];
            out[e] = 1.0f / (1.0f + expf(-m));
        }
    }
}

extern "C" void kernel_launch(void* const* d_in, const int* in_sizes, int n_in,
                              void* d_out, int out_size, void* d_ws, size_t ws_size,
                              hipStream_t stream) {
    const float* node_feats = (const float*)d_in[0];
    const float* edge_feats = (const float*)d_in[1];
    const int*   src        = (const int*)d_in[2];
    const int*   dst        = (const int*)d_in[3];
    const float* W_src      = (const float*)d_in[4];
    const float* b_src      = (const float*)d_in[5];
    const float* W_dst      = (const float*)d_in[6];
    const float* b_dst      = (const float*)d_in[7];
    const float* W_edge     = (const float*)d_in[8];
    const float* b_edge     = (const float*)d_in[9];

    const int n_nodes = in_sizes[0] / FDIM;
    const int n_edges = in_sizes[2];

    float* e_src = (float*)d_ws;
    float* e_dst = e_src + n_nodes;

    // Kernel 1: 2500 node-groups -> 2500 waves -> 625 blocks of 256.
    {
        int ngroups = (n_nodes + 3) / 4;
        int blocks = (ngroups + 3) / 4;      // 4 waves per 256-thread block
        if (blocks > 2048) blocks = 2048;
        node_gates_kernel<<<blocks, 256, 0, stream>>>(
            node_feats, W_src, W_dst, b_src, b_dst, e_src, e_dst, n_nodes);
    }

    // Kernel 2: 80000 edge-groups over 8192 waves (~9.8 groups each).
    {
        int blocks = 2048;
        edge_gate_kernel<<<blocks, 256, 0, stream>>>(
            edge_feats, src, dst, W_edge, b_edge, e_src, e_dst,
            (float*)d_out, n_edges);
    }
}